// Round 10
// baseline (166.195 us; speedup 1.0000x reference)
//
#include <hip/hip_runtime.h>
#include <hip/hip_fp16.h>
#include <cstdint>

#define VOCAB 50000
#define EMB   300
#define SEQ   80
#define HID   128
#define BATCH 4096

typedef __attribute__((ext_vector_type(8))) _Float16 f16x8;
typedef __attribute__((ext_vector_type(4))) float    f32x4;

static __device__ __forceinline__ float fast_tanh(float xv) {
    const float e = __expf(2.f * xv);
    float r;
    asm("v_rcp_f32 %0, %1" : "=v"(r) : "v"(e + 1.f));
    return fmaf(-2.f, r, 1.f);
}
static __device__ __forceinline__ unsigned pack2h(float a, float b) {
    _Float16 ha = (_Float16)a, hb = (_Float16)b;
    unsigned short ua, ub;
    __builtin_memcpy(&ua, &ha, 2); __builtin_memcpy(&ub, &hb, 2);
    return (unsigned)ua | ((unsigned)ub << 16);
}

// ---------------------------------------------------------------------------
// k_wprep: fragment tables.
//  W2 (chunks 0..5119): c=(ks,col,g): W2[c][j] = Wxh[32ks+8g+j][col] (0-pad)
//  W3 (chunks 0..2047): SIGMA-PERMUTED Whh A-frags for the lane-local
//   recurrence: c2=(ct,ks,lane): W3[c2][j] =
//     Whh[32ks + 16*(j>>2) + 4*(lane>>4) + (j&3)][16ct + (lane&15)]
//   With this permutation, next-step B-frags are pure register repacks of
//   the D-layout tanh outputs (no cross-lane movement at all).
// ---------------------------------------------------------------------------
__global__ __launch_bounds__(256) void k_wprep(const float* __restrict__ Wxh,
                                               const float* __restrict__ Whh,
                                               _Float16* __restrict__ W2,
                                               _Float16* __restrict__ W3) {
    const int c = blockIdx.x * 256 + threadIdx.x;
    if (c < 5120) {
        const int ks = c >> 9, rem = c & 511, col = rem >> 2, g = rem & 3;
        f16x8 f;
        #pragma unroll
        for (int j = 0; j < 8; ++j) {
            const int k = 32 * ks + 8 * g + j;
            f[j] = (_Float16)(k < EMB ? Wxh[k * HID + col] : 0.f);
        }
        *reinterpret_cast<f16x8*>(W2 + (size_t)c * 8) = f;
    } else if (c < 7168) {
        const int c2 = c - 5120;
        const int ct = c2 >> 8, ks = (c2 >> 6) & 3, l = c2 & 63;
        const int g = l >> 4, r16 = l & 15;
        f16x8 f;
        #pragma unroll
        for (int j = 0; j < 8; ++j) {
            const int sig = 32 * ks + 16 * (j >> 2) + 4 * g + (j & 3);
            f[j] = (_Float16)Whh[sig * HID + 16 * ct + r16];
        }
        *reinterpret_cast<f16x8*>(W3 + (size_t)c2 * 8) = f;
    }
}

// ---------------------------------------------------------------------------
// k_ptab: P[v][c] = f32( emb[v] @ Wxh + bh ). BARRIER-FREE (R9 structure,
// which measured ~14 us; output now f32 so k_rnn's acc-init is free).
// 256 thr / 4 independent waves; wave owns 16 rows x ALL 128 cols.
// ---------------------------------------------------------------------------
__global__ __launch_bounds__(256, 2) void k_ptab(
    const float*    __restrict__ emb,  // [VOCAB][300]
    const _Float16* __restrict__ W2,   // Wxh frag table
    const float*    __restrict__ bh,   // [128]
    float*          __restrict__ P)    // [VOCAB][128] f32
{
    const int tid = threadIdx.x, lane = tid & 63;
    const int wv = tid >> 6, r16 = lane & 15, g = lane >> 4;
    const int row = blockIdx.x * 64 + wv * 16 + r16;
    const float* rp = emb + (size_t)(row < VOCAB ? row : VOCAB - 1) * EMB;
    const bool wr = (row < VOCAB);

    // e-fragments (B-layout): ef[ks][j] = e[row][32ks+8g+j]
    f16x8 ef[10];
    #pragma unroll
    for (int ks = 0; ks < 9; ++ks) {
        const float4 u0 = *reinterpret_cast<const float4*>(rp + 32 * ks + 8 * g);
        const float4 u1 = *reinterpret_cast<const float4*>(rp + 32 * ks + 8 * g + 4);
        f16x8 f;
        f[0] = (_Float16)u0.x; f[1] = (_Float16)u0.y;
        f[2] = (_Float16)u0.z; f[3] = (_Float16)u0.w;
        f[4] = (_Float16)u1.x; f[5] = (_Float16)u1.y;
        f[6] = (_Float16)u1.z; f[7] = (_Float16)u1.w;
        ef[ks] = f;
    }
    {   // ks = 9: cols 288..299, zero-pad to 320
        f16x8 f;
        #pragma unroll
        for (int j = 0; j < 8; ++j) f[j] = (_Float16)0.f;
        if (g == 0) {
            const float4 u0 = *reinterpret_cast<const float4*>(rp + 288);
            const float4 u1 = *reinterpret_cast<const float4*>(rp + 292);
            f[0] = (_Float16)u0.x; f[1] = (_Float16)u0.y;
            f[2] = (_Float16)u0.z; f[3] = (_Float16)u0.w;
            f[4] = (_Float16)u1.x; f[5] = (_Float16)u1.y;
            f[6] = (_Float16)u1.z; f[7] = (_Float16)u1.w;
        } else if (g == 1) {
            const float4 u0 = *reinterpret_cast<const float4*>(rp + 296);
            f[0] = (_Float16)u0.x; f[1] = (_Float16)u0.y;
            f[2] = (_Float16)u0.z; f[3] = (_Float16)u0.w;
        }
        ef[9] = f;
    }

    float4 bhf[8];
    #pragma unroll
    for (int ct = 0; ct < 8; ++ct)
        bhf[ct] = *reinterpret_cast<const float4*>(bh + 16 * ct + 4 * g);

    f16x8 wA[10], wB[10];
    #pragma unroll
    for (int ks = 0; ks < 10; ++ks)
        wA[ks] = *reinterpret_cast<const f16x8*>(
            W2 + ((size_t)ks * 512 + (size_t)r16 * 4 + g) * 8);

    float* const po = P + (size_t)(wr ? row : 0) * HID;

    #pragma unroll
    for (int ct = 0; ct < 8; ++ct) {
        if (ct < 7) {
            const int coln = 16 * (ct + 1) + r16;
            #pragma unroll
            for (int ks = 0; ks < 10; ++ks)
                ((ct & 1) ? wA : wB)[ks] = *reinterpret_cast<const f16x8*>(
                    W2 + ((size_t)ks * 512 + (size_t)coln * 4 + g) * 8);
        }
        const f16x8* wc = (ct & 1) ? wB : wA;
        f32x4 a0 = {0.f, 0.f, 0.f, 0.f}, a1 = {0.f, 0.f, 0.f, 0.f};
        #pragma unroll
        for (int ks = 0; ks < 10; ks += 2) {
            a0 = __builtin_amdgcn_mfma_f32_16x16x32_f16(wc[ks],     ef[ks],     a0, 0, 0, 0);
            a1 = __builtin_amdgcn_mfma_f32_16x16x32_f16(wc[ks + 1], ef[ks + 1], a1, 0, 0, 0);
        }
        float4 o;
        o.x = a0[0] + a1[0] + bhf[ct].x;
        o.y = a0[1] + a1[1] + bhf[ct].y;
        o.z = a0[2] + a1[2] + bhf[ct].z;
        o.w = a0[3] + a1[3] + bhf[ct].w;
        if (wr) *reinterpret_cast<float4*>(po + ct * 16 + g * 4) = o;
    }
}

// ---------------------------------------------------------------------------
// k_rnn: BARRIER-FREE + EXCHANGE-FREE. One wave per block owns 16 batch rows
// x all 128 cols. Whh sigma-frags staged once in LDS (32 KB; 32 conflict-free
// ds_read_b128/step, hidden under MFMA issue). Per step:
//   acc[ct] = xp float4 (direct f32 C-init, no VALU);
//   32 MFMA (8 independent ct-chains x 4 ks);
//   tanh in place; hf[ks] = register repack via cvt_pk (sigma makes the
//   D->B relayout lane-local -- zero LDS / shuffles / barriers in the loop).
// Live VGPRs ~150 (no spill; R9's failure mode eliminated).
// ---------------------------------------------------------------------------
__global__ __launch_bounds__(64, 1) void k_rnn(
    const int*      __restrict__ x,    // [BATCH][SEQ]
    const float*    __restrict__ P,    // [VOCAB][128] f32 (bh folded)
    const _Float16* __restrict__ W3,   // sigma-permuted Whh frag table
    const float*    __restrict__ Wd,   // [128]
    const float*    __restrict__ bd,   // [1]
    float*          __restrict__ out)  // [BATCH]
{
    __shared__ __align__(16) uint4 whL[2048];   // 32 KB Whh frags
    __shared__ int xidxL[16 * SEQ];             // 5 KB

    const int lane = threadIdx.x;               // 0..63
    const int r16 = lane & 15, g = lane >> 4;
    const int rb = blockIdx.x * 16;

    for (int q = lane; q < 16 * SEQ; q += 64) xidxL[q] = x[rb * SEQ + q];
    {
        const uint4* W3u = (const uint4*)W3;
        for (int q = lane; q < 2048; q += 64) whL[q] = W3u[q];
    }
    __syncthreads();

    // h0 = 0 B-frags
    f16x8 hf[4];
    {
        f16x8 hz;
        #pragma unroll
        for (int j = 0; j < 8; ++j) hz[j] = (_Float16)0.f;
        hf[0] = hz; hf[1] = hz; hf[2] = hz; hf[3] = hz;
    }

    // depth-2 xp register pipeline (float4 per ct)
    float4 xc[8], xn[8];
    {
        const float* p0 = P + (size_t)xidxL[r16 * SEQ + 0] * HID + 4 * g;
        const float* p1 = P + (size_t)xidxL[r16 * SEQ + 1] * HID + 4 * g;
        #pragma unroll
        for (int ct = 0; ct < 8; ++ct) {
            xc[ct] = *reinterpret_cast<const float4*>(p0 + 16 * ct);
            xn[ct] = *reinterpret_cast<const float4*>(p1 + 16 * ct);
        }
    }

    f32x4 acc[8];

#define RNN_STEP(T, XC)                                                        \
    {                                                                          \
        _Pragma("unroll")                                                      \
        for (int ct = 0; ct < 8; ++ct) {                                       \
            acc[ct][0] = XC[ct].x; acc[ct][1] = XC[ct].y;                      \
            acc[ct][2] = XC[ct].z; acc[ct][3] = XC[ct].w;                      \
        }                                                                      \
        if ((T) + 2 < SEQ) {  /* refill XC with xp(T+2); flies under MFMAs */  \
            const float* pp = P +                                              \
                (size_t)xidxL[r16 * SEQ + (T) + 2] * HID + 4 * g;              \
            _Pragma("unroll")                                                  \
            for (int ct = 0; ct < 8; ++ct)                                     \
                XC[ct] = *reinterpret_cast<const float4*>(pp + 16 * ct);       \
        }                                                                      \
        _Pragma("unroll")                                                      \
        for (int ks = 0; ks < 4; ++ks) {                                       \
            _Pragma("unroll")                                                  \
            for (int ct = 0; ct < 8; ++ct) {                                   \
                const f16x8 w = *reinterpret_cast<const f16x8*>(               \
                    &whL[(ct * 4 + ks) * 64 + lane]);                          \
                acc[ct] = __builtin_amdgcn_mfma_f32_16x16x32_f16(              \
                    w, hf[ks], acc[ct], 0, 0, 0);                              \
            }                                                                  \
        }                                                                      \
        _Pragma("unroll")                                                      \
        for (int ct = 0; ct < 8; ++ct) {                                       \
            acc[ct][0] = fast_tanh(acc[ct][0]);                                \
            acc[ct][1] = fast_tanh(acc[ct][1]);                                \
            acc[ct][2] = fast_tanh(acc[ct][2]);                                \
            acc[ct][3] = fast_tanh(acc[ct][3]);                                \
        }                                                                      \
        _Pragma("unroll")                                                      \
        for (int ks = 0; ks < 4; ++ks) {  /* sigma: pure register repack */    \
            uint4 hu;                                                          \
            hu.x = pack2h(acc[2 * ks][0],     acc[2 * ks][1]);                 \
            hu.y = pack2h(acc[2 * ks][2],     acc[2 * ks][3]);                 \
            hu.z = pack2h(acc[2 * ks + 1][0], acc[2 * ks + 1][1]);             \
            hu.w = pack2h(acc[2 * ks + 1][2], acc[2 * ks + 1][3]);             \
            __builtin_memcpy(&hf[ks], &hu, 16);                                \
        }                                                                      \
    }

    #pragma unroll 1
    for (int t = 0; t < SEQ; t += 2) {
        RNN_STEP(t,     xc);
        RNN_STEP(t + 1, xn);
    }
#undef RNN_STEP

    // ---- final dense + sigmoid from f32 h(79) in registers (acc) ----
    float part = 0.f;
    #pragma unroll
    for (int ct = 0; ct < 8; ++ct) {
        const float4 wd = *reinterpret_cast<const float4*>(Wd + 16 * ct + 4 * g);
        part += acc[ct][0] * wd.x + acc[ct][1] * wd.y
              + acc[ct][2] * wd.z + acc[ct][3] * wd.w;
    }
    part += __shfl_xor(part, 16, 64);
    part += __shfl_xor(part, 32, 64);
    if (lane < 16) out[rb + r16] = 1.f / (1.f + expf(-(part + bd[0])));
}

// ---------------------------------------------------------------------------
extern "C" void kernel_launch(void* const* d_in, const int* in_sizes, int n_in,
                              void* d_out, int out_size, void* d_ws, size_t ws_size,
                              hipStream_t stream)
{
    (void)in_sizes; (void)n_in; (void)out_size; (void)ws_size;
    const int*   x   = (const int*)  d_in[0];
    const float* emb = (const float*)d_in[1];
    const float* Wxh = (const float*)d_in[2];
    const float* Whh = (const float*)d_in[3];
    const float* bh  = (const float*)d_in[4];
    const float* Wd  = (const float*)d_in[5];
    const float* bd  = (const float*)d_in[6];
    float* out = (float*)d_out;

    float*    P  = (float*)d_ws;                               // 25.6 MB f32
    _Float16* W2 = (_Float16*)((char*)d_ws + 25600000);        // 80 KB
    _Float16* W3 = (_Float16*)((char*)d_ws + 25681920);        // 32 KB

    k_wprep<<<28, 256, 0, stream>>>(Wxh, Whh, W2, W3);
    k_ptab<<<(VOCAB + 63) / 64, 256, 0, stream>>>(emb, W2, bh, P);
    k_rnn<<<BATCH / 16, 64, 0, stream>>>(x, P, W3, Wd, bd, out);
}

// Round 11
// 127.092 us; speedup vs baseline: 1.3077x; 1.3077x over previous
//
#include <hip/hip_runtime.h>
#include <hip/hip_fp16.h>
#include <cstdint>

#define VOCAB 50000
#define EMB   300
#define SEQ   80
#define HID   128
#define BATCH 4096

typedef __attribute__((ext_vector_type(8))) _Float16 f16x8;
typedef __attribute__((ext_vector_type(4))) float    f32x4;

static __device__ __forceinline__ float fast_tanh(float xv) {
    const float e = __expf(2.f * xv);
    float r;
    asm("v_rcp_f32 %0, %1" : "=v"(r) : "v"(e + 1.f));
    return fmaf(-2.f, r, 1.f);
}
static __device__ __forceinline__ unsigned pack2h(float a, float b) {
    _Float16 ha = (_Float16)a, hb = (_Float16)b;
    unsigned short ua, ub;
    __builtin_memcpy(&ua, &ha, 2); __builtin_memcpy(&ub, &hb, 2);
    return (unsigned)ua | ((unsigned)ub << 16);
}

// ---------------------------------------------------------------------------
// k_wprep: fragment tables.
//  W2 (chunks 0..5119): c=(ks,col,g): W2[c][j] = Wxh[32ks+8g+j][col] (0-pad)
//  W3 (chunks 0..2047): SIGMA-PERMUTED Whh A-frags (HW-verified R10):
//   c2=(ct,ks,lane): W3[c2][j] =
//     Whh[32ks + 16*(j>>2) + 4*(lane>>4) + (j&3)][16ct + (lane&15)]
//   With sigma, next-step B-frags are pure register repacks of the D-layout
//   tanh outputs (no cross-lane movement at all).
// ---------------------------------------------------------------------------
__global__ __launch_bounds__(256) void k_wprep(const float* __restrict__ Wxh,
                                               const float* __restrict__ Whh,
                                               _Float16* __restrict__ W2,
                                               _Float16* __restrict__ W3) {
    const int c = blockIdx.x * 256 + threadIdx.x;
    if (c < 5120) {
        const int ks = c >> 9, rem = c & 511, col = rem >> 2, g = rem & 3;
        f16x8 f;
        #pragma unroll
        for (int j = 0; j < 8; ++j) {
            const int k = 32 * ks + 8 * g + j;
            f[j] = (_Float16)(k < EMB ? Wxh[k * HID + col] : 0.f);
        }
        *reinterpret_cast<f16x8*>(W2 + (size_t)c * 8) = f;
    } else if (c < 7168) {
        const int c2 = c - 5120;
        const int ct = c2 >> 8, ks = (c2 >> 6) & 3, l = c2 & 63;
        const int g = l >> 4, r16 = l & 15;
        f16x8 f;
        #pragma unroll
        for (int j = 0; j < 8; ++j) {
            const int sig = 32 * ks + 16 * (j >> 2) + 4 * g + (j & 3);
            f[j] = (_Float16)Whh[sig * HID + 16 * ct + r16];
        }
        *reinterpret_cast<f16x8*>(W3 + (size_t)c2 * 8) = f;
    }
}

// ---------------------------------------------------------------------------
// k_ptab: P[v][c] = f32( emb[v] @ Wxh + bh ). BARRIER-FREE (unchanged from
// R10). 256 thr / 4 independent waves; wave owns 16 rows x ALL 128 cols.
// ---------------------------------------------------------------------------
__global__ __launch_bounds__(256, 2) void k_ptab(
    const float*    __restrict__ emb,  // [VOCAB][300]
    const _Float16* __restrict__ W2,   // Wxh frag table
    const float*    __restrict__ bh,   // [128]
    float*          __restrict__ P)    // [VOCAB][128] f32
{
    const int tid = threadIdx.x, lane = tid & 63;
    const int wv = tid >> 6, r16 = lane & 15, g = lane >> 4;
    const int row = blockIdx.x * 64 + wv * 16 + r16;
    const float* rp = emb + (size_t)(row < VOCAB ? row : VOCAB - 1) * EMB;
    const bool wr = (row < VOCAB);

    f16x8 ef[10];
    #pragma unroll
    for (int ks = 0; ks < 9; ++ks) {
        const float4 u0 = *reinterpret_cast<const float4*>(rp + 32 * ks + 8 * g);
        const float4 u1 = *reinterpret_cast<const float4*>(rp + 32 * ks + 8 * g + 4);
        f16x8 f;
        f[0] = (_Float16)u0.x; f[1] = (_Float16)u0.y;
        f[2] = (_Float16)u0.z; f[3] = (_Float16)u0.w;
        f[4] = (_Float16)u1.x; f[5] = (_Float16)u1.y;
        f[6] = (_Float16)u1.z; f[7] = (_Float16)u1.w;
        ef[ks] = f;
    }
    {
        f16x8 f;
        #pragma unroll
        for (int j = 0; j < 8; ++j) f[j] = (_Float16)0.f;
        if (g == 0) {
            const float4 u0 = *reinterpret_cast<const float4*>(rp + 288);
            const float4 u1 = *reinterpret_cast<const float4*>(rp + 292);
            f[0] = (_Float16)u0.x; f[1] = (_Float16)u0.y;
            f[2] = (_Float16)u0.z; f[3] = (_Float16)u0.w;
            f[4] = (_Float16)u1.x; f[5] = (_Float16)u1.y;
            f[6] = (_Float16)u1.z; f[7] = (_Float16)u1.w;
        } else if (g == 1) {
            const float4 u0 = *reinterpret_cast<const float4*>(rp + 296);
            f[0] = (_Float16)u0.x; f[1] = (_Float16)u0.y;
            f[2] = (_Float16)u0.z; f[3] = (_Float16)u0.w;
        }
        ef[9] = f;
    }

    float4 bhf[8];
    #pragma unroll
    for (int ct = 0; ct < 8; ++ct)
        bhf[ct] = *reinterpret_cast<const float4*>(bh + 16 * ct + 4 * g);

    f16x8 wA[10], wB[10];
    #pragma unroll
    for (int ks = 0; ks < 10; ++ks)
        wA[ks] = *reinterpret_cast<const f16x8*>(
            W2 + ((size_t)ks * 512 + (size_t)r16 * 4 + g) * 8);

    float* const po = P + (size_t)(wr ? row : 0) * HID;

    #pragma unroll
    for (int ct = 0; ct < 8; ++ct) {
        if (ct < 7) {
            const int coln = 16 * (ct + 1) + r16;
            #pragma unroll
            for (int ks = 0; ks < 10; ++ks)
                ((ct & 1) ? wA : wB)[ks] = *reinterpret_cast<const f16x8*>(
                    W2 + ((size_t)ks * 512 + (size_t)coln * 4 + g) * 8);
        }
        const f16x8* wc = (ct & 1) ? wB : wA;
        f32x4 a0 = {0.f, 0.f, 0.f, 0.f}, a1 = {0.f, 0.f, 0.f, 0.f};
        #pragma unroll
        for (int ks = 0; ks < 10; ks += 2) {
            a0 = __builtin_amdgcn_mfma_f32_16x16x32_f16(wc[ks],     ef[ks],     a0, 0, 0, 0);
            a1 = __builtin_amdgcn_mfma_f32_16x16x32_f16(wc[ks + 1], ef[ks + 1], a1, 0, 0, 0);
        }
        float4 o;
        o.x = a0[0] + a1[0] + bhf[ct].x;
        o.y = a0[1] + a1[1] + bhf[ct].y;
        o.z = a0[2] + a1[2] + bhf[ct].z;
        o.w = a0[3] + a1[3] + bhf[ct].w;
        if (wr) *reinterpret_cast<float4*>(po + ct * 16 + g * 4) = o;
    }
}

// ---------------------------------------------------------------------------
// k_rnn: ZERO-LDS loop. One wave per block owns 16 batch rows x all 128 cols.
// Whh sigma-frags in registers/AGPRs (loaded once; 128 regs). Index pipeline
// in registers via global loads (depth-4); xp gather depth-2 into f32x4 regs
// that C-init the ks=0 MFMAs directly. Steady-state loop touches ONLY
// vmcnt-domain loads (prefetched ~2 steps = ~1400 cyc ahead), MFMA, VALU:
// no ds_read, no barriers, no lgkm events at all.
// ---------------------------------------------------------------------------
__global__ __launch_bounds__(64, 1) void k_rnn(
    const int*      __restrict__ x,    // [BATCH][SEQ]
    const float*    __restrict__ P,    // [VOCAB][128] f32 (bh folded)
    const _Float16* __restrict__ W3,   // sigma-permuted Whh frag table
    const float*    __restrict__ Wd,   // [128]
    const float*    __restrict__ bd,   // [1]
    float*          __restrict__ out)  // [BATCH]
{
    const int lane = threadIdx.x;               // 0..63
    const int r16 = lane & 15, g = lane >> 4;
    const int rb = blockIdx.x * 16;
    const int xbase = (rb + r16) * SEQ;

    // ---- Whh fragments resident in registers/AGPRs ----
    f16x8 wh[8][4];
    #pragma unroll
    for (int ct = 0; ct < 8; ++ct)
        #pragma unroll
        for (int ks = 0; ks < 4; ++ks)
            wh[ct][ks] = *reinterpret_cast<const f16x8*>(
                W3 + ((size_t)(ct * 4 + ks) * 64 + lane) * 8);

    // ---- h0 = 0 B-frags ----
    f16x8 hf[4];
    {
        f16x8 hz;
        #pragma unroll
        for (int j = 0; j < 8; ++j) hz[j] = (_Float16)0.f;
        hf[0] = hz; hf[1] = hz; hf[2] = hz; hf[3] = hz;
    }

    // ---- register index pipeline (depth 4) + xp gather pipeline (depth 2) --
    int idxA = x[xbase + 0];
    int idxB = x[xbase + 1];
    f32x4 xc[8], xn[8];
    {
        const float* p0 = P + (size_t)idxA * HID + 4 * g;
        const float* p1 = P + (size_t)idxB * HID + 4 * g;
        #pragma unroll
        for (int ct = 0; ct < 8; ++ct) {
            xc[ct] = *reinterpret_cast<const f32x4*>(p0 + 16 * ct);
            xn[ct] = *reinterpret_cast<const f32x4*>(p1 + 16 * ct);
        }
    }
    idxA = x[xbase + 2];
    idxB = x[xbase + 3];

    f32x4 acc[8];

#define RNN_STEP(T, XC, IDX)                                                   \
    {                                                                          \
        /* ks=0: C-init directly from gathered xp (no VALU) */                 \
        _Pragma("unroll")                                                      \
        for (int ct = 0; ct < 8; ++ct)                                         \
            acc[ct] = __builtin_amdgcn_mfma_f32_16x16x32_f16(                  \
                wh[ct][0], hf[0], XC[ct], 0, 0, 0);                            \
        /* refill XC with gather(T+2); refill IDX with idx(T+4) */             \
        if ((T) + 2 < SEQ) {                                                   \
            const float* pp = P + (size_t)(IDX) * HID + 4 * g;                 \
            _Pragma("unroll")                                                  \
            for (int ct = 0; ct < 8; ++ct)                                     \
                XC[ct] = *reinterpret_cast<const f32x4*>(pp + 16 * ct);        \
        }                                                                      \
        if ((T) + 4 < SEQ) IDX = x[xbase + (T) + 4];                           \
        _Pragma("unroll")                                                      \
        for (int ks = 1; ks < 4; ++ks)                                         \
            _Pragma("unroll")                                                  \
            for (int ct = 0; ct < 8; ++ct)                                     \
                acc[ct] = __builtin_amdgcn_mfma_f32_16x16x32_f16(              \
                    wh[ct][ks], hf[ks], acc[ct], 0, 0, 0);                     \
        _Pragma("unroll")                                                      \
        for (int ct = 0; ct < 8; ++ct) {                                       \
            acc[ct][0] = fast_tanh(acc[ct][0]);                                \
            acc[ct][1] = fast_tanh(acc[ct][1]);                                \
            acc[ct][2] = fast_tanh(acc[ct][2]);                                \
            acc[ct][3] = fast_tanh(acc[ct][3]);                                \
        }                                                                      \
        _Pragma("unroll")                                                      \
        for (int ks = 0; ks < 4; ++ks) {  /* sigma: lane-local repack */       \
            uint4 hu;                                                          \
            hu.x = pack2h(acc[2 * ks][0],     acc[2 * ks][1]);                 \
            hu.y = pack2h(acc[2 * ks][2],     acc[2 * ks][3]);                 \
            hu.z = pack2h(acc[2 * ks + 1][0], acc[2 * ks + 1][1]);             \
            hu.w = pack2h(acc[2 * ks + 1][2], acc[2 * ks + 1][3]);             \
            __builtin_memcpy(&hf[ks], &hu, 16);                                \
        }                                                                      \
    }

    #pragma unroll 1
    for (int t = 0; t < SEQ; t += 2) {
        RNN_STEP(t,     xc, idxA);
        RNN_STEP(t + 1, xn, idxB);
    }
#undef RNN_STEP

    // ---- final dense + sigmoid from f32 h(79) in registers (acc) ----
    float part = 0.f;
    #pragma unroll
    for (int ct = 0; ct < 8; ++ct) {
        const float4 wd = *reinterpret_cast<const float4*>(Wd + 16 * ct + 4 * g);
        part += acc[ct][0] * wd.x + acc[ct][1] * wd.y
              + acc[ct][2] * wd.z + acc[ct][3] * wd.w;
    }
    part += __shfl_xor(part, 16, 64);
    part += __shfl_xor(part, 32, 64);
    if (lane < 16) out[rb + r16] = 1.f / (1.f + expf(-(part + bd[0])));
}

// ---------------------------------------------------------------------------
extern "C" void kernel_launch(void* const* d_in, const int* in_sizes, int n_in,
                              void* d_out, int out_size, void* d_ws, size_t ws_size,
                              hipStream_t stream)
{
    (void)in_sizes; (void)n_in; (void)out_size; (void)ws_size;
    const int*   x   = (const int*)  d_in[0];
    const float* emb = (const float*)d_in[1];
    const float* Wxh = (const float*)d_in[2];
    const float* Whh = (const float*)d_in[3];
    const float* bh  = (const float*)d_in[4];
    const float* Wd  = (const float*)d_in[5];
    const float* bd  = (const float*)d_in[6];
    float* out = (float*)d_out;

    float*    P  = (float*)d_ws;                               // 25.6 MB f32
    _Float16* W2 = (_Float16*)((char*)d_ws + 25600000);        // 80 KB
    _Float16* W3 = (_Float16*)((char*)d_ws + 25681920);        // 32 KB

    k_wprep<<<28, 256, 0, stream>>>(Wxh, Whh, W2, W3);
    k_ptab<<<(VOCAB + 63) / 64, 256, 0, stream>>>(emb, W2, bh, P);
    k_rnn<<<BATCH / 16, 64, 0, stream>>>(x, P, W3, Wd, bd, out);
}